// Round 6
// baseline (3539.373 us; speedup 1.0000x reference)
//
#include <hip/hip_runtime.h>

#define B_ 512
#define L_ 1000
#define H_ 128
#define G_ 512  // 4*H

typedef _Float16 v8h __attribute__((ext_vector_type(8)));
typedef _Float16 h2t __attribute__((ext_vector_type(2)));
typedef float v4f __attribute__((ext_vector_type(4)));

__device__ __forceinline__ float sigmoid_f(float x) {
  return __builtin_amdgcn_rcpf(1.0f + __builtin_amdgcn_exp2f(-1.4426950408889634f * x));
}
__device__ __forceinline__ float tanh_f(float x) {
  return 1.0f - 2.0f * __builtin_amdgcn_rcpf(1.0f + __builtin_amdgcn_exp2f(2.8853900817779268f * x));
}

// Replicated B-fragment buffer: chunk (kt, ls) holds the 16-B B-operand
// fragment h_{ls&1}[kt*32 + (ls>>4)*8 + j], j=0..7 (f16). The +(ls>>3) pad
// destaggers the update-phase scatter writes (without it they'd be 16-way
// bank-conflicted); compute-phase reads are lane-linear 16B and conflict-free
// for any contiguous layout.
// ROUND-5 BUG FIX: kt stride was 1088 but a kt-block spans (63+7)*16+16 =
// 1136 B -> chunks ls>=61 aliased the next kt block and the scatter corrupted
// h fragments (absmax 1.66e-2). Stride is now 1152 (>=1136).
#define FB_KT_STRIDE 1152
#define FB_BYTES     4608   // 4 * FB_KT_STRIDE; max used = 3*1152+70*16+16 = 4592
#define FB2_OFF      FB_BYTES
__device__ __forceinline__ int fb_addr(int kt, int lane_slot) {
  return kt * FB_KT_STRIDE + (lane_slot + (lane_slot >> 3)) * 16;
}

#define MFMA16(a, b, c) __builtin_amdgcn_mfma_f32_16x16x32_f16((a), (b), (c), 0, 0, 0)

// 256 blocks x 1024 threads (16 waves), one block/CU, 2 batch rows/block.
// Wave w holds A-fragments (f16) of gates [32w,32w+32) of w_hh1, w_ih2,
// w_hh2 = 96 dwords/thread (AGPR-resident, round 4 verified no spill).
// Fused step (3 barriers):
//   U1 (thr 0..127):  g1 = g1carry + wx*x + b -> c1,h1 -> scatter fb1
//   C  (all waves):   g2 = A2i@h1 + A2h@h2 -> gbuf2 ; g1carry' = A1@h1 -> gbuf1
//   U2 (thr 128..255): c2,h2 -> scatter fb2 ; out = <h2, w_lin> + b
__global__ __launch_bounds__(1024) void lstm_mfma(
    const float* __restrict__ x,
    const float* __restrict__ w_ih1,
    const float* __restrict__ w_hh1,
    const float* __restrict__ b_ih1,
    const float* __restrict__ b_hh1,
    const float* __restrict__ w_ih2,
    const float* __restrict__ w_hh2,
    const float* __restrict__ b_ih2,
    const float* __restrict__ b_hh2,
    const float* __restrict__ w_lin,
    const float* __restrict__ b_lin,
    float* __restrict__ out)
{
  __shared__ __align__(16) float xlds[2][L_];        // block's 2 x-rows
  __shared__ __align__(16) float gbuf1[2][G_];       // g1 carry (raw, C-layout)
  __shared__ __align__(16) float gbuf2[2][G_];       // g2 raw
  __shared__ __align__(16) unsigned char fbarr[2 * FB_BYTES];  // fb1 | fb2
  __shared__ __align__(16) float wxb[G_];            // w_ih1 column
  __shared__ __align__(16) float bbb1[G_];           // b_ih1+b_hh1
  __shared__ __align__(16) float bbb2[G_];           // b_ih2+b_hh2
  __shared__ __align__(16) float wlb[H_];            // w_lin row

  const int tid   = threadIdx.x;
  const int wv    = tid >> 6;
  const int lane  = tid & 63;
  const int quad  = lane >> 4;
  const int m15   = lane & 15;
  const int r0    = blockIdx.x * 2;
  const int gbase = wv * 32;

  // ---- one-time staging ----
  for (int i = tid; i < 2 * L_; i += 1024) ((float*)xlds)[i] = x[r0 * L_ + i];
  if (tid < G_) {
    wxb[tid]  = w_ih1[tid];
    bbb1[tid] = b_ih1[tid] + b_hh1[tid];
    bbb2[tid] = b_ih2[tid] + b_hh2[tid];
    gbuf1[0][tid] = 0.f;        // g1 carry = A1 @ h1_init(=0)
    gbuf1[1][tid] = 0.f;
  }
  if (tid < H_) wlb[tid] = w_lin[tid];
  // fb1/fb2 must read as h_init = 0 at t=0 (zero whole array incl. pads)
  for (int i = tid; i < 2 * FB_BYTES / 4; i += 1024) ((unsigned*)fbarr)[i] = 0u;

  // ---- per-wave weight A-fragments (f16): A[m][k], m=m15, k=quad*8+j ----
  v8h A1[2][4], A2i[2][4], A2h[2][4];
#pragma unroll
  for (int mt = 0; mt < 2; ++mt) {
    const int grow = (gbase + mt * 16 + m15) * H_;
#pragma unroll
    for (int kt = 0; kt < 4; ++kt) {
      const int koff = kt * 32 + quad * 8;
      float4 a, b;
      a = *(const float4*)(w_hh1 + grow + koff);
      b = *(const float4*)(w_hh1 + grow + koff + 4);
      A1[mt][kt] = v8h{(_Float16)a.x, (_Float16)a.y, (_Float16)a.z, (_Float16)a.w,
                       (_Float16)b.x, (_Float16)b.y, (_Float16)b.z, (_Float16)b.w};
      a = *(const float4*)(w_ih2 + grow + koff);
      b = *(const float4*)(w_ih2 + grow + koff + 4);
      A2i[mt][kt] = v8h{(_Float16)a.x, (_Float16)a.y, (_Float16)a.z, (_Float16)a.w,
                        (_Float16)b.x, (_Float16)b.y, (_Float16)b.z, (_Float16)b.w};
      a = *(const float4*)(w_hh2 + grow + koff);
      b = *(const float4*)(w_hh2 + grow + koff + 4);
      A2h[mt][kt] = v8h{(_Float16)a.x, (_Float16)a.y, (_Float16)a.z, (_Float16)a.w,
                        (_Float16)b.x, (_Float16)b.y, (_Float16)b.z, (_Float16)b.w};
    }
  }

  float c1s0 = 0.f, c1s1 = 0.f;  // layer-1 cell state (threads 0..127)
  float c2s0 = 0.f, c2s1 = 0.f;  // layer-2 cell state (threads 128..255)
  const float blv = b_lin[0];

  __syncthreads();

  for (int t = 0; t < L_; ++t) {
    // ---- U1: layer-1 update; thread owns hids (2l, 2l+1) of row=tid>>6 ----
    if (tid < 128) {
      const int row = tid >> 6;
      const int l   = lane;
      const int e   = 2 * l;
      const float xv = xlds[row][t];
      float2 gi = *(const float2*)&gbuf1[row][e];
      float2 gf = *(const float2*)&gbuf1[row][128 + e];
      float2 gg = *(const float2*)&gbuf1[row][256 + e];
      float2 go = *(const float2*)&gbuf1[row][384 + e];
      float2 wxi = *(const float2*)&wxb[e],       bi = *(const float2*)&bbb1[e];
      float2 wxf = *(const float2*)&wxb[128 + e], bf = *(const float2*)&bbb1[128 + e];
      float2 wxg = *(const float2*)&wxb[256 + e], bg = *(const float2*)&bbb1[256 + e];
      float2 wxo = *(const float2*)&wxb[384 + e], bo = *(const float2*)&bbb1[384 + e];
      float i0 = sigmoid_f(gi.x + wxi.x * xv + bi.x);
      float i1 = sigmoid_f(gi.y + wxi.y * xv + bi.y);
      float f0 = sigmoid_f(gf.x + wxf.x * xv + bf.x);
      float f1 = sigmoid_f(gf.y + wxf.y * xv + bf.y);
      float g0 = tanh_f(gg.x + wxg.x * xv + bg.x);
      float g1 = tanh_f(gg.y + wxg.y * xv + bg.y);
      float o0 = sigmoid_f(go.x + wxo.x * xv + bo.x);
      float o1 = sigmoid_f(go.y + wxo.y * xv + bo.y);
      c1s0 = f0 * c1s0 + i0 * g0;
      c1s1 = f1 * c1s1 + i1 * g1;
      h2t hp = h2t{(_Float16)(o0 * tanh_f(c1s0)), (_Float16)(o1 * tanh_f(c1s1))};
      const unsigned val = __builtin_bit_cast(unsigned, hp);
      // scatter into the 8 replica chunks holding k = 2l, 2l+1 for this row
      const int kt   = l >> 4;
      const int q    = (l >> 2) & 3;
      const int boff = (l & 3) * 4;
#pragma unroll
      for (int i = 0; i < 8; ++i) {
        const int ls = q * 16 + row + 2 * i;
        *(unsigned*)(fbarr + fb_addr(kt, ls) + boff) = val;
      }
    }
    __syncthreads();

    // ---- C: all 16 waves; 8 conflict-free b128 B-loads feed 24 MFMA ----
    {
      v4f accG0 = {0.f, 0.f, 0.f, 0.f}, accG1 = {0.f, 0.f, 0.f, 0.f};
      v4f accC0 = {0.f, 0.f, 0.f, 0.f}, accC1 = {0.f, 0.f, 0.f, 0.f};
      const unsigned char* fbl = fbarr + fb_addr(0, lane);
#pragma unroll
      for (int kt = 0; kt < 4; ++kt) {
        v8h b1 = *(const v8h*)(fbl + kt * FB_KT_STRIDE);
        v8h b2 = *(const v8h*)(fbl + FB2_OFF + kt * FB_KT_STRIDE);
        accG0 = MFMA16(A2i[0][kt], b1, accG0);
        accG1 = MFMA16(A2i[1][kt], b1, accG1);
        accC0 = MFMA16(A1[0][kt],  b1, accC0);
        accC1 = MFMA16(A1[1][kt],  b1, accC1);
        accG0 = MFMA16(A2h[0][kt], b2, accG0);
        accG1 = MFMA16(A2h[1][kt], b2, accG1);
      }
      if (m15 < 2) {  // C-layout: col=m15=batch row, row=quad*4+reg=gate
        *(v4f*)&gbuf2[m15][gbase + quad * 4]      = accG0;
        *(v4f*)&gbuf2[m15][gbase + 16 + quad * 4] = accG1;
        *(v4f*)&gbuf1[m15][gbase + quad * 4]      = accC0;
        *(v4f*)&gbuf1[m15][gbase + 16 + quad * 4] = accC1;
      }
    }
    __syncthreads();

    // ---- U2: layer-2 update + output; threads 128..255 ----
    if (tid >= 128 && tid < 256) {
      const int row = (tid >> 6) & 1;
      const int l   = lane;
      const int e   = 2 * l;
      float2 gi = *(const float2*)&gbuf2[row][e];
      float2 gf = *(const float2*)&gbuf2[row][128 + e];
      float2 gg = *(const float2*)&gbuf2[row][256 + e];
      float2 go = *(const float2*)&gbuf2[row][384 + e];
      float2 bi = *(const float2*)&bbb2[e];
      float2 bf = *(const float2*)&bbb2[128 + e];
      float2 bg = *(const float2*)&bbb2[256 + e];
      float2 bo = *(const float2*)&bbb2[384 + e];
      float i0 = sigmoid_f(gi.x + bi.x);
      float i1 = sigmoid_f(gi.y + bi.y);
      float f0 = sigmoid_f(gf.x + bf.x);
      float f1 = sigmoid_f(gf.y + bf.y);
      float g0 = tanh_f(gg.x + bg.x);
      float g1 = tanh_f(gg.y + bg.y);
      float o0 = sigmoid_f(go.x + bo.x);
      float o1 = sigmoid_f(go.y + bo.y);
      c2s0 = f0 * c2s0 + i0 * g0;
      c2s1 = f1 * c2s1 + i1 * g1;
      float h0 = o0 * tanh_f(c2s0);
      float h1 = o1 * tanh_f(c2s1);
      h2t hp = h2t{(_Float16)h0, (_Float16)h1};
      const unsigned val = __builtin_bit_cast(unsigned, hp);
      const int kt   = l >> 4;
      const int q    = (l >> 2) & 3;
      const int boff = (l & 3) * 4;
#pragma unroll
      for (int i = 0; i < 8; ++i) {
        const int ls = q * 16 + row + 2 * i;
        *(unsigned*)(fbarr + FB2_OFF + fb_addr(kt, ls) + boff) = val;
      }
      float2 wl = *(const float2*)&wlb[e];
      float p = h0 * wl.x + h1 * wl.y;
#pragma unroll
      for (int s = 1; s < 64; s <<= 1) p += __shfl_xor(p, s, 64);
      if (l == 0) out[(r0 + row) * L_ + t] = p + blv;
    }
    __syncthreads();
  }
}

extern "C" void kernel_launch(void* const* d_in, const int* in_sizes, int n_in,
                              void* d_out, int out_size, void* d_ws, size_t ws_size,
                              hipStream_t stream) {
  const float* x     = (const float*)d_in[0];
  const float* w_ih1 = (const float*)d_in[1];
  const float* w_hh1 = (const float*)d_in[2];
  const float* b_ih1 = (const float*)d_in[3];
  const float* b_hh1 = (const float*)d_in[4];
  const float* w_ih2 = (const float*)d_in[5];
  const float* w_hh2 = (const float*)d_in[6];
  const float* b_ih2 = (const float*)d_in[7];
  const float* b_hh2 = (const float*)d_in[8];
  const float* w_lin = (const float*)d_in[9];
  const float* b_lin = (const float*)d_in[10];

  lstm_mfma<<<B_ / 2, 1024, 0, stream>>>(
      x, w_ih1, w_hh1, b_ih1, b_hh1, w_ih2, w_hh2, b_ih2, b_hh2,
      w_lin, b_lin, (float*)d_out);
}

// Round 7
// 2148.722 us; speedup vs baseline: 1.6472x; 1.6472x over previous
//
#include <hip/hip_runtime.h>

#define B_ 512
#define L_ 1000
#define H_ 128
#define G_ 512  // 4*H

typedef _Float16 v8h __attribute__((ext_vector_type(8)));
typedef _Float16 h2t __attribute__((ext_vector_type(2)));
typedef float v4f __attribute__((ext_vector_type(4)));

__device__ __forceinline__ float sigmoid_f(float x) {
  return __builtin_amdgcn_rcpf(1.0f + __builtin_amdgcn_exp2f(-1.4426950408889634f * x));
}
__device__ __forceinline__ float tanh_f(float x) {
  return 1.0f - 2.0f * __builtin_amdgcn_rcpf(1.0f + __builtin_amdgcn_exp2f(2.8853900817779268f * x));
}

// h storage in B-FRAGMENT ORDER: chunk (kt, quad, row) at byte offset
// kt*144 + quad*32 + row*16 holds h_row[kt*32 + quad*8 + j], j=0..7 (f16).
// Compute-phase read addr (per kt): quad*32 + (m15&1)*16 -> 8 distinct
// addresses whose bank groups (4kt + 8quad + 4row) mod 32 cover all 32 banks
// with ONE address per bank -> pure broadcast, zero conflicts (round 4/6
// killer: row stride 256B put 64 lanes in banks 0-15, 2 addrs/bank = 2.1e8+
// conflict cycles). Update-phase write: one dword per thread, banks
// (4kt + 8quad + row*4 + (l&3)) mod 32 -> max 2 lanes/bank = free (m136).
// kt stride 144 (not 128) destaggers kt blocks so write lanes sharing
// (quad,l&3) across kt don't alias one bank 4-way.
#define FB_KT 144

#define MFMA16(a, b, c) __builtin_amdgcn_mfma_f32_16x16x32_f16((a), (b), (c), 0, 0, 0)

// 256 blocks x 1024 threads (16 waves), one block/CU, 2 batch rows/block.
// Wave w holds f16 A-fragments of gates [32w,32w+32) of w_hh1, w_ih2, w_hh2
// = 96 dwords/thread (AGPR-resident; round 4/6 verified no spill).
// TWO barriers per step (round 6 had 3): U1(t) and U2(t-1) are independent,
// so they run concurrently (waves 0-1 | 2-3, one per SIMD):
//   U:  thr 0..127:  g1=gbuf1+wx*x+b -> c1,h1(t) -> hb1
//       thr 128..255: g2=gbuf2+b -> c2,h2(t-1) -> hb2, out(t-1)
//   C:  all 16 waves: gbuf2' = A2i@h1(t) + A2h@h2(t-1); gbuf1' = A1@h1(t)
// Loop t=0..L inclusive; U1 guarded t<L, U2 guarded t>0 (epilogue iter).
__global__ __launch_bounds__(1024) void lstm_mfma(
    const float* __restrict__ x,
    const float* __restrict__ w_ih1,
    const float* __restrict__ w_hh1,
    const float* __restrict__ b_ih1,
    const float* __restrict__ b_hh1,
    const float* __restrict__ w_ih2,
    const float* __restrict__ w_hh2,
    const float* __restrict__ b_ih2,
    const float* __restrict__ b_hh2,
    const float* __restrict__ w_lin,
    const float* __restrict__ b_lin,
    float* __restrict__ out)
{
  __shared__ __align__(16) float xlds[2][L_];        // block's 2 x-rows
  __shared__ __align__(16) float gbuf1[2][G_];       // g1 carry (raw, C-layout)
  __shared__ __align__(16) float gbuf2[2][G_];       // g2 raw
  __shared__ __align__(16) unsigned char hb1[4 * FB_KT];  // h1, fragment order
  __shared__ __align__(16) unsigned char hb2[4 * FB_KT];  // h2, fragment order
  __shared__ __align__(16) float wxb[G_];            // w_ih1 column
  __shared__ __align__(16) float bbb1[G_];           // b_ih1+b_hh1
  __shared__ __align__(16) float bbb2[G_];           // b_ih2+b_hh2
  __shared__ __align__(16) float wlb[H_];            // w_lin row

  const int tid   = threadIdx.x;
  const int wv    = tid >> 6;
  const int lane  = tid & 63;
  const int quad  = lane >> 4;
  const int m15   = lane & 15;
  const int r0    = blockIdx.x * 2;
  const int gbase = wv * 32;

  // ---- one-time staging ----
  for (int i = tid; i < 2 * L_; i += 1024) ((float*)xlds)[i] = x[r0 * L_ + i];
  if (tid < G_) {
    wxb[tid]  = w_ih1[tid];
    bbb1[tid] = b_ih1[tid] + b_hh1[tid];
    bbb2[tid] = b_ih2[tid] + b_hh2[tid];
    gbuf1[0][tid] = 0.f;        // g1 carry = A1 @ h1_init(=0)
    gbuf1[1][tid] = 0.f;
  }
  if (tid < H_) wlb[tid] = w_lin[tid];
  if (tid < 2 * FB_KT) {        // hb1/hb2 read as h=0 before first write
    ((unsigned*)hb1)[tid & (FB_KT - 16)] = 0u;  // (mask trick avoids OOB; see below)
  }
  // simpler + exact: zero both buffers fully
  for (int i = tid; i < (2 * 4 * FB_KT) / 4; i += 1024) {
    if (i < 4 * FB_KT / 4) ((unsigned*)hb1)[i] = 0u;
    else                   ((unsigned*)hb2)[i - 4 * FB_KT / 4] = 0u;
  }

  // ---- per-wave weight A-fragments (f16): A[m][k], m=m15, k=quad*8+j ----
  v8h A1[2][4], A2i[2][4], A2h[2][4];
#pragma unroll
  for (int mt = 0; mt < 2; ++mt) {
    const int grow = (gbase + mt * 16 + m15) * H_;
#pragma unroll
    for (int kt = 0; kt < 4; ++kt) {
      const int koff = kt * 32 + quad * 8;
      float4 a, b;
      a = *(const float4*)(w_hh1 + grow + koff);
      b = *(const float4*)(w_hh1 + grow + koff + 4);
      A1[mt][kt] = v8h{(_Float16)a.x, (_Float16)a.y, (_Float16)a.z, (_Float16)a.w,
                       (_Float16)b.x, (_Float16)b.y, (_Float16)b.z, (_Float16)b.w};
      a = *(const float4*)(w_ih2 + grow + koff);
      b = *(const float4*)(w_ih2 + grow + koff + 4);
      A2i[mt][kt] = v8h{(_Float16)a.x, (_Float16)a.y, (_Float16)a.z, (_Float16)a.w,
                        (_Float16)b.x, (_Float16)b.y, (_Float16)b.z, (_Float16)b.w};
      a = *(const float4*)(w_hh2 + grow + koff);
      b = *(const float4*)(w_hh2 + grow + koff + 4);
      A2h[mt][kt] = v8h{(_Float16)a.x, (_Float16)a.y, (_Float16)a.z, (_Float16)a.w,
                        (_Float16)b.x, (_Float16)b.y, (_Float16)b.z, (_Float16)b.w};
    }
  }

  float c1s0 = 0.f, c1s1 = 0.f;  // layer-1 cell state (threads 0..127)
  float c2s0 = 0.f, c2s1 = 0.f;  // layer-2 cell state (threads 128..255)
  const float blv = b_lin[0];

  // per-thread hbuf write offset (update phases): k=2l -> kt=l>>4,
  // quad'=(l>>2)&3, byte = kt*144 + quad'*32 + row*16 + (l&3)*4
  const int hwo = (lane >> 4) * FB_KT + ((lane >> 2) & 3) * 32 + (lane & 3) * 4;

  __syncthreads();

  for (int t = 0; t <= L_; ++t) {
    // ---- U-phase: U1(t) on thr 0..127 || U2(t-1) on thr 128..255 ----
    if (tid < 128) {
      if (t < L_) {
        const int row = tid >> 6;
        const int e   = 2 * lane;
        const float xv = xlds[row][t];
        float2 gi = *(const float2*)&gbuf1[row][e];
        float2 gf = *(const float2*)&gbuf1[row][128 + e];
        float2 gg = *(const float2*)&gbuf1[row][256 + e];
        float2 go = *(const float2*)&gbuf1[row][384 + e];
        float2 wxi = *(const float2*)&wxb[e],       bi = *(const float2*)&bbb1[e];
        float2 wxf = *(const float2*)&wxb[128 + e], bf = *(const float2*)&bbb1[128 + e];
        float2 wxg = *(const float2*)&wxb[256 + e], bg = *(const float2*)&bbb1[256 + e];
        float2 wxo = *(const float2*)&wxb[384 + e], bo = *(const float2*)&bbb1[384 + e];
        float i0 = sigmoid_f(gi.x + wxi.x * xv + bi.x);
        float i1 = sigmoid_f(gi.y + wxi.y * xv + bi.y);
        float f0 = sigmoid_f(gf.x + wxf.x * xv + bf.x);
        float f1 = sigmoid_f(gf.y + wxf.y * xv + bf.y);
        float g0 = tanh_f(gg.x + wxg.x * xv + bg.x);
        float g1 = tanh_f(gg.y + wxg.y * xv + bg.y);
        float o0 = sigmoid_f(go.x + wxo.x * xv + bo.x);
        float o1 = sigmoid_f(go.y + wxo.y * xv + bo.y);
        c1s0 = f0 * c1s0 + i0 * g0;
        c1s1 = f1 * c1s1 + i1 * g1;
        h2t hp = h2t{(_Float16)(o0 * tanh_f(c1s0)), (_Float16)(o1 * tanh_f(c1s1))};
        *(unsigned*)(hb1 + row * 16 + hwo) = __builtin_bit_cast(unsigned, hp);
      }
    } else if (tid < 256) {
      if (t > 0) {
        const int row = (tid >> 6) & 1;
        const int e   = 2 * lane;
        float2 gi = *(const float2*)&gbuf2[row][e];
        float2 gf = *(const float2*)&gbuf2[row][128 + e];
        float2 gg = *(const float2*)&gbuf2[row][256 + e];
        float2 go = *(const float2*)&gbuf2[row][384 + e];
        float2 bi = *(const float2*)&bbb2[e];
        float2 bf = *(const float2*)&bbb2[128 + e];
        float2 bg = *(const float2*)&bbb2[256 + e];
        float2 bo = *(const float2*)&bbb2[384 + e];
        float i0 = sigmoid_f(gi.x + bi.x);
        float i1 = sigmoid_f(gi.y + bi.y);
        float f0 = sigmoid_f(gf.x + bf.x);
        float f1 = sigmoid_f(gf.y + bf.y);
        float g0 = tanh_f(gg.x + bg.x);
        float g1 = tanh_f(gg.y + bg.y);
        float o0 = sigmoid_f(go.x + bo.x);
        float o1 = sigmoid_f(go.y + bo.y);
        c2s0 = f0 * c2s0 + i0 * g0;
        c2s1 = f1 * c2s1 + i1 * g1;
        float h0 = o0 * tanh_f(c2s0);
        float h1 = o1 * tanh_f(c2s1);
        h2t hp = h2t{(_Float16)h0, (_Float16)h1};
        *(unsigned*)(hb2 + row * 16 + hwo) = __builtin_bit_cast(unsigned, hp);
        float2 wl = *(const float2*)&wlb[e];
        float p = h0 * wl.x + h1 * wl.y;
#pragma unroll
        for (int s = 1; s < 64; s <<= 1) p += __shfl_xor(p, s, 64);
        if (lane == 0) out[(r0 + row) * L_ + (t - 1)] = p + blv;
      }
    }
    __syncthreads();

    // ---- C-phase: all 16 waves; 8 broadcast b128 reads feed 24 MFMA ----
    if (t < L_) {
      v4f accG0 = {0.f, 0.f, 0.f, 0.f}, accG1 = {0.f, 0.f, 0.f, 0.f};
      v4f accC0 = {0.f, 0.f, 0.f, 0.f}, accC1 = {0.f, 0.f, 0.f, 0.f};
      const int roff = quad * 32 + (m15 & 1) * 16;
#pragma unroll
      for (int kt = 0; kt < 4; ++kt) {
        v8h b1 = *(const v8h*)(hb1 + kt * FB_KT + roff);
        v8h b2 = *(const v8h*)(hb2 + kt * FB_KT + roff);
        accG0 = MFMA16(A2i[0][kt], b1, accG0);
        accG1 = MFMA16(A2i[1][kt], b1, accG1);
        accC0 = MFMA16(A1[0][kt],  b1, accC0);
        accC1 = MFMA16(A1[1][kt],  b1, accC1);
        accG0 = MFMA16(A2h[0][kt], b2, accG0);
        accG1 = MFMA16(A2h[1][kt], b2, accG1);
      }
      if (m15 < 2) {  // C-layout: col=m15=batch row, row=quad*4+reg=gate
        *(v4f*)&gbuf2[m15][gbase + quad * 4]      = accG0;
        *(v4f*)&gbuf2[m15][gbase + 16 + quad * 4] = accG1;
        *(v4f*)&gbuf1[m15][gbase + quad * 4]      = accC0;
        *(v4f*)&gbuf1[m15][gbase + 16 + quad * 4] = accC1;
      }
    }
    __syncthreads();
  }
}

extern "C" void kernel_launch(void* const* d_in, const int* in_sizes, int n_in,
                              void* d_out, int out_size, void* d_ws, size_t ws_size,
                              hipStream_t stream) {
  const float* x     = (const float*)d_in[0];
  const float* w_ih1 = (const float*)d_in[1];
  const float* w_hh1 = (const float*)d_in[2];
  const float* b_ih1 = (const float*)d_in[3];
  const float* b_hh1 = (const float*)d_in[4];
  const float* w_ih2 = (const float*)d_in[5];
  const float* w_hh2 = (const float*)d_in[6];
  const float* b_ih2 = (const float*)d_in[7];
  const float* b_hh2 = (const float*)d_in[8];
  const float* w_lin = (const float*)d_in[9];
  const float* b_lin = (const float*)d_in[10];

  lstm_mfma<<<B_ / 2, 1024, 0, stream>>>(
      x, w_ih1, w_hh1, b_ih1, b_hh1, w_ih2, w_hh2, b_ih2, b_hh2,
      w_lin, b_lin, (float*)d_out);
}